// Round 9
// baseline (545.633 us; speedup 1.0000x reference)
//
#include <hip/hip_runtime.h>
#include <hip/hip_fp16.h>
#include <math.h>

// GCN 3-layer: out = Â relu(Â relu(Â x W1 + b1) W2 + b2) W3 + b3, Â = D^-1/2(A+I)D^-1/2
// Layer 3 reordered: Â(h2 W3) = (Â h2) W3.
// 9-dispatch pipeline with a DIRECT node-level CSR build (no H matrix, no packed
// two-level radix):
//   memset(cnt) -> K1[dst hist via global atomics on cnt[100k]  ||  GEMM1]
//   K2[98 blocks: deterministic prefix (re-sum cnt[0..base)) + local scan ->
//      row_start + cur + dinv + gh row-scale]
//   K3[edge scatter: pos = atomicAdd(&cur[dst],1); ssrc[pos] = src]
//   agg1 ; GEMM2 ; agg2 ; agg3 ; GEMM3
// Lessons encoded: R5 = atomic-with-return on FEW shared counters serializes
// (100k node counters are fine); R6 = no in-kernel grid barriers; R7 = no
// agg+GEMM fusion (agg needs many short blocks).
// All dense GEMMs v_mfma_f32_16x16x32_f16; intermediates fp16 (128B rows).
// agg: R3-verified form (1 node/wave, even/odd half-waves, 16 gathers in flight).

#define IN_DIM 128
#define HID 64
#define OUT_DIM 112
#define SCAN_TILE 1024   // nodes per K2 block
#define NHIST 256        // histogram blocks in K1

typedef _Float16 f16x8 __attribute__((ext_vector_type(8)));
typedef float f32x4 __attribute__((ext_vector_type(4)));

// ---- W^T staging into LDS (fp16, +8-half pad) ----
template <int K, int C>
__device__ __forceinline__ void stage_w(const float* __restrict__ W, _Float16* Wt) {
  constexpr int KP = K + 8;
  for (int idx = threadIdx.x; idx < K * C; idx += 256) {
    int k = idx / C, c = idx % C;
    Wt[c * KP + k] = (_Float16)W[idx];
  }
}

// ---- MFMA GEMM compute (Wt staged + synced by caller) ----
// G[r][c] = (X.W)*(DINV?dinv[r]:1) + (BIAS?bias[c]:0); 4 waves x 16 rows = 64/block.
// Layouts (verified): A/B: row|col=lane&15, k=(lane>>4)*8+j ; C/D: col=lane&15,
// row=(lane>>4)*4+reg.
template <int K, int C, bool XH, bool DINV, bool BIAS, bool OUTH>
__device__ __forceinline__ void gemm_compute(int blk, const void* __restrict__ Xv,
                                             const float* __restrict__ dinv,
                                             const float* __restrict__ bias,
                                             void* __restrict__ G, int n,
                                             const _Float16* Wt) {
  constexpr int KP = K + 8;
  constexpr int NT = C / 16;
  constexpr int KS = K / 32;
  const int tid = threadIdx.x;
  const int l = tid & 63;
  const int rbase = blk * 64 + (tid >> 6) * 16;
  const int kg = (l >> 4) * 8;
  const int c16 = l & 15;

  int arow = rbase + c16;
  if (arow >= n) arow = n - 1;
  f16x8 af[KS];
  if (XH) {
    const _Float16* Xh = reinterpret_cast<const _Float16*>(Xv);
#pragma unroll
    for (int ks = 0; ks < KS; ++ks)
      af[ks] = *reinterpret_cast<const f16x8*>(&Xh[(size_t)arow * K + ks * 32 + kg]);
  } else {
    const float* Xf = reinterpret_cast<const float*>(Xv);
#pragma unroll
    for (int ks = 0; ks < KS; ++ks) {
      float4 u0 = *reinterpret_cast<const float4*>(&Xf[(size_t)arow * K + ks * 32 + kg]);
      float4 u1 = *reinterpret_cast<const float4*>(&Xf[(size_t)arow * K + ks * 32 + kg + 4]);
      f16x8 a;
      a[0] = (_Float16)u0.x; a[1] = (_Float16)u0.y; a[2] = (_Float16)u0.z; a[3] = (_Float16)u0.w;
      a[4] = (_Float16)u1.x; a[5] = (_Float16)u1.y; a[6] = (_Float16)u1.z; a[7] = (_Float16)u1.w;
      af[ks] = a;
    }
  }

  f32x4 acc[NT];
#pragma unroll
  for (int nt = 0; nt < NT; ++nt) acc[nt] = (f32x4){0.f, 0.f, 0.f, 0.f};

#pragma unroll
  for (int ks = 0; ks < KS; ++ks) {
#pragma unroll
    for (int nt = 0; nt < NT; ++nt) {
      f16x8 bf = *reinterpret_cast<const f16x8*>(&Wt[(nt * 16 + c16) * KP + ks * 32 + kg]);
      acc[nt] = __builtin_amdgcn_mfma_f32_16x16x32_f16(af[ks], bf, acc[nt], 0, 0, 0);
    }
  }

#pragma unroll
  for (int r = 0; r < 4; ++r) {
    int grow = rbase + (l >> 4) * 4 + r;
    if (grow < n) {
      float s = DINV ? dinv[grow] : 1.0f;
#pragma unroll
      for (int nt = 0; nt < NT; ++nt) {
        float v = acc[nt][r] * s;
        if (BIAS) v += bias[nt * 16 + c16];
        if (OUTH)
          reinterpret_cast<__half*>(G)[(size_t)grow * C + nt * 16 + c16] = __float2half(v);
        else
          reinterpret_cast<float*>(G)[(size_t)grow * C + nt * 16 + c16] = v;
      }
    }
  }
}

// ---- standalone MFMA GEMM kernel ----
template <int K, int C, bool XH, bool DINV, bool BIAS, bool OUTH>
__global__ __launch_bounds__(256) void mfma_gemm_kernel(const void* __restrict__ Xv,
                                                        const float* __restrict__ W,
                                                        const float* __restrict__ dinv,
                                                        const float* __restrict__ bias,
                                                        void* __restrict__ G, int n) {
  __shared__ _Float16 Wt[C * (K + 8)];
  stage_w<K, C>(W, Wt);
  __syncthreads();
  gemm_compute<K, C, XH, DINV, BIAS, OUTH>(blockIdx.x, Xv, dinv, bias, G, n, Wt);
}

// ---- K1: blocks [0,NHIST) = dst histogram (global atomics) ; rest = GEMM1 ----
__global__ __launch_bounds__(256) void hist_gemm1_kernel(
    const float* __restrict__ x, const float* __restrict__ W1, __half* __restrict__ gh,
    int n, const int* __restrict__ dst, int* __restrict__ cnt, int E) {
  __shared__ _Float16 Wt[HID * (IN_DIM + 8)];
  const int tid = threadIdx.x;
  if ((int)blockIdx.x < NHIST) {
    // 1.6M atomics spread over 100k L2-resident counters: low contention
    for (int i = blockIdx.x * 256 + tid; i < E; i += NHIST * 256)
      atomicAdd(&cnt[dst[i]], 1);
  } else {
    stage_w<IN_DIM, HID>(W1, Wt);
    __syncthreads();
    gemm_compute<IN_DIM, HID, false, false, false, true>(
        (int)blockIdx.x - NHIST, x, nullptr, nullptr, gh, n, Wt);
  }
}

// ---- K2: deterministic prefix + row_start/cur/dinv + gh row-scale ----
// Block b re-sums cnt[0..b*1024) for its base (L2-hot, ~20MB total), scans its
// own 1024 node counts locally, then bulk-scales its gh rows by dinv.
__global__ __launch_bounds__(256) void scan_fused_kernel(
    const int* __restrict__ cnt, int* __restrict__ row_start, int* __restrict__ cur,
    float* __restrict__ dinv, __half* __restrict__ gh, int n, int E) {
  const int t = threadIdx.x;
  const int base = blockIdx.x * SCAN_TILE;
  __shared__ int wred[4];
  __shared__ int sh[256];
  __shared__ float sdi[SCAN_TILE];

  // prefix over all preceding nodes
  int partial = 0;
  for (int i = t; i < base; i += 256) partial += cnt[i];
#pragma unroll
  for (int off = 1; off < 64; off <<= 1) partial += __shfl_xor(partial, off);
  const int lane = t & 63, wv = t >> 6;
  if (lane == 0) wred[wv] = partial;

  // local degs: thread t owns nodes base+4t .. base+4t+3
  const int i0 = base + t * 4;
  int v0 = 0, v1 = 0, v2 = 0, v3 = 0;
  if (i0 + 4 <= n) {
    int4 v = *reinterpret_cast<const int4*>(&cnt[i0]);
    v0 = v.x; v1 = v.y; v2 = v.z; v3 = v.w;
  } else {
    if (i0 + 0 < n) v0 = cnt[i0 + 0];
    if (i0 + 1 < n) v1 = cnt[i0 + 1];
    if (i0 + 2 < n) v2 = cnt[i0 + 2];
    if (i0 + 3 < n) v3 = cnt[i0 + 3];
  }
  int s = v0 + v1 + v2 + v3;
  sh[t] = s;
  __syncthreads();
  const int blockbase = wred[0] + wred[1] + wred[2] + wred[3];
  for (int off = 1; off < 256; off <<= 1) {
    int u = (t >= off) ? sh[t - off] : 0;
    __syncthreads();
    sh[t] += u;
    __syncthreads();
  }
  int run = blockbase + sh[t] - s;
  int p0 = run, p1 = run + v0, p2 = p1 + v1, p3 = p2 + v2;
  if (i0 + 4 <= n) {
    *reinterpret_cast<int4*>(&row_start[i0]) = make_int4(p0, p1, p2, p3);
    *reinterpret_cast<int4*>(&cur[i0]) = make_int4(p0, p1, p2, p3);
  } else {
    if (i0 + 0 < n) { row_start[i0 + 0] = p0; cur[i0 + 0] = p0; }
    if (i0 + 1 < n) { row_start[i0 + 1] = p1; cur[i0 + 1] = p1; }
    if (i0 + 2 < n) { row_start[i0 + 2] = p2; cur[i0 + 2] = p2; }
    if (i0 + 3 < n) { row_start[i0 + 3] = p3; cur[i0 + 3] = p3; }
  }
  // dinv (+1 = self loop)
  float d0 = 1.0f / sqrtf((float)(v0 + 1));
  float d1 = 1.0f / sqrtf((float)(v1 + 1));
  float d2 = 1.0f / sqrtf((float)(v2 + 1));
  float d3 = 1.0f / sqrtf((float)(v3 + 1));
  if (i0 + 0 < n) dinv[i0 + 0] = d0;
  if (i0 + 1 < n) dinv[i0 + 1] = d1;
  if (i0 + 2 < n) dinv[i0 + 2] = d2;
  if (i0 + 3 < n) dinv[i0 + 3] = d3;
  sdi[t * 4 + 0] = d0; sdi[t * 4 + 1] = d1; sdi[t * 4 + 2] = d2; sdi[t * 4 + 3] = d3;
  if (blockIdx.x == 0 && t == 0) row_start[n] = E;
  __syncthreads();
  // scale this block's gh rows by dinv (1024 nodes x 32 half2, coalesced)
  __half2* g2 = reinterpret_cast<__half2*>(gh);
  for (int i = t; i < SCAN_TILE * 32; i += 256) {
    int nd = i >> 5;
    int node = base + nd;
    if (node < n) {
      int q = i & 31;
      float2 f = __half22float2(g2[(size_t)node * 32 + q]);
      float d = sdi[nd];
      g2[(size_t)node * 32 + q] = __floats2half2_rn(f.x * d, f.y * d);
    }
  }
}

// ---- K3: edge scatter via per-node atomic cursors (100k counters, low contention) ----
__global__ __launch_bounds__(256) void scatter_kernel(const int* __restrict__ src,
                                                      const int* __restrict__ dst,
                                                      int* __restrict__ cur,
                                                      int* __restrict__ ssrc, int E) {
  const int stride = gridDim.x * 256;
  for (int i = blockIdx.x * 256 + threadIdx.x; i < E; i += stride) {
    int d = dst[i];
    int pos = atomicAdd(&cur[d], 1);
    ssrc[pos] = src[i];
  }
}

// ---- agg: 4 nodes per block (one per wave).  R3-verified structure. ----
// out[d][c] = post( dinv[d]*(g[d][c] + sum_e g[ssrc[e]][c]) [+bias] )  (fp16 out)
template <bool RELU, bool BIAS, bool TSCALE>
__global__ __launch_bounds__(256) void agg_kernel(const __half* __restrict__ g,
                                                  const int* __restrict__ row_start,
                                                  const int* __restrict__ ssrc,
                                                  const float* __restrict__ dinv,
                                                  const float* __restrict__ bias,
                                                  __half* __restrict__ out, int n) {
  const int tid = threadIdx.x;
  const int wv = tid >> 6;
  const int lane = tid & 63;
  const int h = lane >> 5;   // half-wave: 0 = even edges (+ self + odd tail), 1 = odd
  const int q = lane & 31;   // channel-pair index: channels {2q, 2q+1}
  int node = blockIdx.x * 4 + wv;
  if (node >= n) return;
  const __half2* g2 = reinterpret_cast<const __half2*>(g);

  int e0 = row_start[node];
  int e1 = row_start[node + 1];
  int deg = e1 - e0;
  float2 acc = make_float2(0.f, 0.f);
  if (h == 0) {  // self-loop term, counted once
    float2 sv = __half22float2(g2[(size_t)node * 32 + q]);
    acc.x = sv.x; acc.y = sv.y;
  }
  const int pairs = deg >> 1;
  const int base = e0 + h;  // this half's first edge (stride 2)
  int k = 0;
  for (; k + 8 <= pairs; k += 8) {  // 16 edges in flight per wave
    int idx[8];
#pragma unroll
    for (int i = 0; i < 8; ++i) idx[i] = ssrc[base + 2 * (k + i)];
    __half2 v[8];
#pragma unroll
    for (int i = 0; i < 8; ++i) v[i] = g2[(size_t)idx[i] * 32 + q];
#pragma unroll
    for (int i = 0; i < 8; ++i) {
      float2 f = __half22float2(v[i]);
      acc.x += f.x; acc.y += f.y;
    }
  }
  for (; k + 2 <= pairs; k += 2) {
    int i0 = ssrc[base + 2 * k];
    int i1 = ssrc[base + 2 * (k + 1)];
    float2 f0 = __half22float2(g2[(size_t)i0 * 32 + q]);
    float2 f1 = __half22float2(g2[(size_t)i1 * 32 + q]);
    acc.x += f0.x + f1.x; acc.y += f0.y + f1.y;
  }
  for (; k < pairs; ++k) {
    int i0 = ssrc[base + 2 * k];
    float2 f = __half22float2(g2[(size_t)i0 * 32 + q]);
    acc.x += f.x; acc.y += f.y;
  }
  if ((deg & 1) && h == 0) {  // odd edge handled once, by half 0
    int i0 = ssrc[e1 - 1];
    float2 f = __half22float2(g2[(size_t)i0 * 32 + q]);
    acc.x += f.x; acc.y += f.y;
  }
  // combine even/odd halves
  acc.x += __shfl_xor(acc.x, 32);
  acc.y += __shfl_xor(acc.y, 32);

  if (h == 0) {
    float di = dinv[node];
    float rx = acc.x * di, ry = acc.y * di;
    if (BIAS) {
      float2 bv = *reinterpret_cast<const float2*>(&bias[2 * q]);
      rx += bv.x; ry += bv.y;
    }
    if (RELU) { rx = fmaxf(rx, 0.f); ry = fmaxf(ry, 0.f); }
    if (TSCALE) { rx *= di; ry *= di; }
    reinterpret_cast<__half2*>(out)[(size_t)node * 32 + q] = __floats2half2_rn(rx, ry);
  }
}

extern "C" void kernel_launch(void* const* d_in, const int* in_sizes, int n_in,
                              void* d_out, int out_size, void* d_ws, size_t ws_size,
                              hipStream_t stream) {
  const float* x = (const float*)d_in[0];
  const int* ei = (const int*)d_in[1];
  const float* W1 = (const float*)d_in[2];
  const float* b1 = (const float*)d_in[3];
  const float* W2 = (const float*)d_in[4];
  const float* b2 = (const float*)d_in[5];
  const float* W3 = (const float*)d_in[6];
  const float* b3 = (const float*)d_in[7];
  float* out = (float*)d_out;

  const int n = in_sizes[0] / IN_DIM;  // 100000
  const int E = in_sizes[1] / 2;       // 1600000
  const int* src = ei;
  const int* dst = ei + E;

  char* p = (char*)d_ws;
  auto alloc = [&](size_t bytes) {
    char* q = p;
    p += (bytes + 255) & ~(size_t)255;
    return q;
  };
  int* cnt = (int*)alloc((size_t)n * 4);
  float* dinv = (float*)alloc((size_t)n * 4);
  int* row_start = (int*)alloc((size_t)(n + 1) * 4);
  int* cur = (int*)alloc((size_t)n * 4);
  int* ssrc = (int*)alloc((size_t)E * 4);
  __half* gh  = (__half*)alloc((size_t)n * HID * 2);  // GEMM1 out; reused as GEMM2 out
  __half* h1h = (__half*)alloc((size_t)n * HID * 2);  // h1; reused as z
  __half* th  = (__half*)alloc((size_t)n * HID * 2);  // t (agg2 out, agg3 gather src)

  const int GG = (n + 63) / 64;                    // 1563 GEMM tiles
  const int AGRID = (n + 3) / 4;                   // 25000 agg blocks
  const int NB = (n + SCAN_TILE - 1) / SCAN_TILE;  // 98 scan blocks

  // ---- CSR build (direct, node-level) + GEMM1 overlapped ----
  hipMemsetAsync(cnt, 0, (size_t)n * 4, stream);
  hist_gemm1_kernel<<<NHIST + GG, 256, 0, stream>>>(x, W1, gh, n, dst, cnt, E);
  scan_fused_kernel<<<NB, 256, 0, stream>>>(cnt, row_start, cur, dinv, gh, n, E);
  scatter_kernel<<<2048, 256, 0, stream>>>(src, dst, cur, ssrc, E);

  // ---- layer 1: h1 = relu(dinv*(gh[self] + Σ gh[s]) + b1)   (gh pre-scaled) ----
  agg_kernel<true, true, false><<<AGRID, 256, 0, stream>>>(gh, row_start, ssrc, dinv, b1, h1h, n);

  // ---- layer 2: gh = (h1 W2)*dinv_row ; t = relu(dinv*agg + b2)*dinv ----
  mfma_gemm_kernel<HID, HID, true, true, false, true><<<GG, 256, 0, stream>>>(h1h, W2, dinv, nullptr, gh, n);
  agg_kernel<true, true, true><<<AGRID, 256, 0, stream>>>(gh, row_start, ssrc, dinv, b2, th, n);

  // ---- layer 3 (reordered): z = dinv*(t + Σ t[s]) ; out = z W3 + b3 (fp32) ----
  agg_kernel<false, false, false><<<AGRID, 256, 0, stream>>>(th, row_start, ssrc, dinv, nullptr, h1h, n);
  mfma_gemm_kernel<HID, OUT_DIM, true, false, true, false><<<GG, 256, 0, stream>>>(h1h, W3, nullptr, b3, out, n);
}